// Round 10
// baseline (162.255 us; speedup 1.0000x reference)
//
#include <hip/hip_runtime.h>
#include <math.h>

#define T_LEN 2097152
#define K 8
#define D 4
#define CHUNK 8
#define TPB 256
#define NBLK (T_LEN / (CHUNK * TPB))  // 1024 blocks
#define MSTRIDE 65                    // LDS matrix stride (floats)

// ws layout (floats): [0..63] Tr; [64..71] a; [72..103] b; [104..135] c; [136..143] alpha0
// [256..) bp (NBLK*64 floats), then bs (NBLK ints), then counter (1 int)

__device__ __forceinline__ void renorm_mat(float P[K][K], int& shift) {
    float mx = 0.f;
#pragma unroll
    for (int i = 0; i < K; ++i)
#pragma unroll
        for (int j = 0; j < K; ++j) mx = fmaxf(mx, P[i][j]);
    int ex = (__float_as_int(mx) >> 23) & 255;
    float scale = __int_as_float((254 - ex) << 23); // 2^(127-ex)
    shift += ex - 127;
#pragma unroll
    for (int i = 0; i < K; ++i)
#pragma unroll
        for (int j = 0; j < K; ++j) P[i][j] *= scale;
}

__device__ __forceinline__ void mat_combine(const float L[K][K], const float R[K][K], float C[K][K]) {
#pragma unroll
    for (int i = 0; i < K; ++i) {
        float q[K];
#pragma unroll
        for (int j = 0; j < K; ++j) q[j] = L[i][0] * R[0][j];
#pragma unroll
        for (int k = 1; k < K; ++k)
#pragma unroll
            for (int j = 0; j < K; ++j) q[j] = fmaf(L[i][k], R[k][j], q[j]);
#pragma unroll
        for (int j = 0; j < K; ++j) C[i][j] = q[j];
    }
}

__device__ __forceinline__ void combine_stream(const float* __restrict__ Lp,
                                               const float* __restrict__ Rp,
                                               float C[K][K]) {
#pragma unroll
    for (int k = 0; k < K; ++k) {
        float Lc[K], Rr[K];
#pragma unroll
        for (int i = 0; i < K; ++i) Lc[i] = Lp[i * 8 + k];
#pragma unroll
        for (int j = 0; j < K; ++j) Rr[j] = Rp[k * 8 + j];
        if (k == 0) {
#pragma unroll
            for (int i = 0; i < K; ++i)
#pragma unroll
                for (int j = 0; j < K; ++j) C[i][j] = Lc[i] * Rr[j];
        } else {
#pragma unroll
            for (int i = 0; i < K; ++i)
#pragma unroll
                for (int j = 0; j < K; ++j) C[i][j] = fmaf(Lc[i], Rr[j], C[i][j]);
        }
    }
}

// Hybrid tree over 256 time-ordered per-thread matrices (lm: 128 slots, stride 65).
// Level 1 masked through LDS; levels 2..8 packed (one combine per lane).
__device__ __forceinline__ void hybrid_tree(float P[K][K], int& shift, float* lm, int* lsh) {
    const int t = threadIdx.x;
    if ((t & 1) == 0) {
#pragma unroll
        for (int i = 0; i < K; ++i)
#pragma unroll
            for (int j = 0; j < K; ++j) lm[(t >> 1) * MSTRIDE + i * 8 + j] = P[i][j];
        lsh[t >> 1] = shift;
    }
    __syncthreads();
    if (t & 1) {
        float L[K][K];
#pragma unroll
        for (int i = 0; i < K; ++i)
#pragma unroll
            for (int k = 0; k < K; ++k) L[i][k] = lm[(t >> 1) * MSTRIDE + i * 8 + k];
        float C[K][K];
        mat_combine(L, P, C); // L earlier in time
        int ns = shift + lsh[t >> 1];
        renorm_mat(C, ns);
#pragma unroll
        for (int i = 0; i < K; ++i)
#pragma unroll
            for (int j = 0; j < K; ++j) lm[(t >> 1) * MSTRIDE + i * 8 + j] = C[i][j];
        lsh[t >> 1] = ns;
    }
    __syncthreads();
    const int lane = t & 63, w = t >> 6;
#pragma unroll 1
    for (int r = 1; r <= 7; ++r) {
        const int c = 64 >> (r - 1);
        const int S = 1 << (r - 1);
        const int aw = r & 1;
        if (w == aw && lane < c) {
            const int li = (2 * lane) * S, ri = li + S;
            float C[K][K];
            combine_stream(&lm[li * MSTRIDE], &lm[ri * MSTRIDE], C);
            int ns = lsh[li] + lsh[ri];
            renorm_mat(C, ns);
#pragma unroll
            for (int i = 0; i < K; ++i)
#pragma unroll
                for (int j = 0; j < K; ++j) lm[li * MSTRIDE + i * 8 + j] = C[i][j];
            lsh[li] = ns;
        }
        __syncthreads();
    }
}

// 64-thread parallel setup (keeps main's consts uniform -> SGPR)
__global__ void hmm_setup(const float* __restrict__ x,
                          const float* __restrict__ ut,
                          const float* __restrict__ up,
                          const float* __restrict__ mn,
                          const float* __restrict__ lsd,
                          float* __restrict__ ws) {
    const int lane = threadIdx.x;
    const float L2PI = 1.83787706640934548356f;
    const float LOG2E = 1.44269504088896340736f;

    float v = ut[lane];
    float m = v;
    m = fmaxf(m, __shfl_xor(m, 1));
    m = fmaxf(m, __shfl_xor(m, 2));
    m = fmaxf(m, __shfl_xor(m, 4));
    float e = expf(v - m);
    float s = e;
    s += __shfl_xor(s, 1); s += __shfl_xor(s, 2); s += __shfl_xor(s, 4);
    ws[lane] = e / s;

    float pv = up[lane & 7];
    float pm = pv;
    pm = fmaxf(pm, __shfl_xor(pm, 1));
    pm = fmaxf(pm, __shfl_xor(pm, 2));
    pm = fmaxf(pm, __shfl_xor(pm, 4));
    float pe = expf(pv - pm);
    float ps = pe;
    ps += __shfl_xor(ps, 1); ps += __shfl_xor(ps, 2); ps += __shfl_xor(ps, 4);
    float pival = pe / ps;

    int k = (lane & 31) >> 2, d = lane & 3;
    float lv = lsd[k * D + d];
    float mu = mn[k * D + d];
    float iv = expf(-2.f * lv);
    float bn = mu * iv;
    float cn = -0.5f * iv;
    float aterm = -0.5f * L2PI - lv - 0.5f * mu * mu * iv;
    float ak = aterm;
    ak += __shfl_xor(ak, 1); ak += __shfl_xor(ak, 2);
    if (lane < 32) {
        ws[72 + lane]  = bn * LOG2E;
        ws[104 + lane] = cn * LOG2E;
        if (d == 0) ws[64 + k] = ak * LOG2E;
    }

    float xd = x[d];
    float part = (cn * xd + bn) * xd + aterm;
    part += __shfl_xor(part, 1); part += __shfl_xor(part, 2);
    float pik = __shfl(pival, k);
    if (lane < 32 && d == 0) ws[136 + k] = pik * expf(part);
}

__global__ __launch_bounds__(TPB) void hmm_main(const float* __restrict__ x,
                                                const float* __restrict__ cst,
                                                float* __restrict__ bp,
                                                int* __restrict__ bs,
                                                int* __restrict__ counter,
                                                float* __restrict__ out) {
    __shared__ float lm[128 * MSTRIDE];
    __shared__ int lsh[128];
    __shared__ int lastFlag;
    const int tid = blockIdx.x * TPB + threadIdx.x;

    float Tr[K][K];
#pragma unroll
    for (int i = 0; i < K; ++i)
#pragma unroll
        for (int j = 0; j < K; ++j) Tr[i][j] = cst[i * K + j];
    float ca[K], cb[K][D], cc[K][D];
#pragma unroll
    for (int k = 0; k < K; ++k) {
        ca[k] = cst[64 + k];
#pragma unroll
        for (int d = 0; d < D; ++d) {
            cb[k][d] = cst[72 + k * D + d];
            cc[k][d] = cst[104 + k * D + d];
        }
    }

    const float4* xv = reinterpret_cast<const float4*>(x) + (size_t)tid * CHUNK;

    float P[K][K];
    int shift = 0;
    if (tid == 0) {
#pragma unroll
        for (int i = 0; i < K; ++i)
#pragma unroll
            for (int j = 0; j < K; ++j) P[i][j] = (i == j) ? cst[136 + i] : 0.0f;
    } else {
        float4 x0 = xv[0];
        float e[K];
#pragma unroll
        for (int j = 0; j < K; ++j) {
            float em = ca[j];
            em = fmaf(fmaf(cc[j][0], x0.x, cb[j][0]), x0.x, em);
            em = fmaf(fmaf(cc[j][1], x0.y, cb[j][1]), x0.y, em);
            em = fmaf(fmaf(cc[j][2], x0.z, cb[j][2]), x0.z, em);
            em = fmaf(fmaf(cc[j][3], x0.w, cb[j][3]), x0.w, em);
            e[j] = exp2f(em);
        }
#pragma unroll
        for (int i = 0; i < K; ++i)
#pragma unroll
            for (int j = 0; j < K; ++j) P[i][j] = Tr[i][j] * e[j];
    }

    // scan: P <- (P*Tr) .col e_t ; pow2 renorm every 2nd step folded into next e
    float fcarry = 0.0f;
    int icarry = 0;
    float4 xnext = xv[1];
#pragma unroll 1
    for (int t = 1; t < CHUNK; ++t) {
        float4 xt = xnext;
        int tn = (t + 1 < CHUNK) ? (t + 1) : t;
        xnext = xv[tn];
        float e[K];
#pragma unroll
        for (int j = 0; j < K; ++j) {
            float em = ca[j];
            em = fmaf(fmaf(cc[j][0], xt.x, cb[j][0]), xt.x, em);
            em = fmaf(fmaf(cc[j][1], xt.y, cb[j][1]), xt.y, em);
            em = fmaf(fmaf(cc[j][2], xt.z, cb[j][2]), xt.z, em);
            em = fmaf(fmaf(cc[j][3], xt.w, cb[j][3]), xt.w, em);
            e[j] = exp2f(em + fcarry);
        }
        shift -= icarry;
#pragma unroll
        for (int i = 0; i < K; ++i) {
            float q[K];
#pragma unroll
            for (int j = 0; j < K; ++j) q[j] = P[i][0] * Tr[0][j];
#pragma unroll
            for (int k = 1; k < K; ++k)
#pragma unroll
                for (int j = 0; j < K; ++j) q[j] = fmaf(P[i][k], Tr[k][j], q[j]);
#pragma unroll
            for (int j = 0; j < K; ++j) P[i][j] = q[j] * e[j];
        }
        if ((t & 1) == 0) {
            float mx = 0.f;
#pragma unroll
            for (int i = 0; i < K; ++i)
#pragma unroll
                for (int j = 0; j < K; ++j) mx = fmaxf(mx, P[i][j]);
            int ex = (__float_as_int(mx) >> 23) & 255;
            icarry = 127 - ex;
            fcarry = (float)icarry;
        } else {
            icarry = 0;
            fcarry = 0.0f;
        }
    }
    renorm_mat(P, shift);

    hybrid_tree(P, shift, lm, lsh);

    // block product -> global; last block to finish reduces all blocks
    if (threadIdx.x == 0) {
        float4* o4 = reinterpret_cast<float4*>(bp + (size_t)blockIdx.x * 64);
        const float4* l4 = reinterpret_cast<const float4*>(lm);
#pragma unroll
        for (int q = 0; q < 16; ++q) o4[q] = l4[q];
        bs[blockIdx.x] = lsh[0];
        __threadfence(); // release
        int old = atomicAdd(counter, 1);
        lastFlag = (old == NBLK - 1) ? 1 : 0;
    }
    __syncthreads();
    if (!lastFlag) return;
    __threadfence(); // acquire

    // ---- final phase (last block only): 1024 mats -> 256 serial(4) -> tree -> out
    {
        const int t = threadIdx.x;
        const int base = t * 4;
        float Pf[K][K];
        {
            const float4* p4 = reinterpret_cast<const float4*>(bp + (size_t)base * 64);
            float4* dst = reinterpret_cast<float4*>(&Pf[0][0]);
#pragma unroll
            for (int q = 0; q < 16; ++q) dst[q] = p4[q];
        }
        int sh = bs[base];
#pragma unroll 1
        for (int r = 1; r < 4; ++r) {
            const float* Rp = bp + (size_t)(base + r) * 64;
            float C[K][K];
            combine_stream(&Pf[0][0], Rp, C);
            sh += bs[base + r];
            renorm_mat(C, sh);
#pragma unroll
            for (int i = 0; i < K; ++i)
#pragma unroll
                for (int j = 0; j < K; ++j) Pf[i][j] = C[i][j];
        }
        __syncthreads();
        hybrid_tree(Pf, sh, lm, lsh);
    }
    if (threadIdx.x == 0) {
        double s = 0.0;
#pragma unroll
        for (int i = 0; i < K; ++i)
#pragma unroll
            for (int j = 0; j < K; ++j) s += (double)lm[i * 8 + j];
        out[0] = (float)(log(s) + (double)lsh[0] * 0.69314718055994530942);
    }
}

extern "C" void kernel_launch(void* const* d_in, const int* in_sizes, int n_in,
                              void* d_out, int out_size, void* d_ws, size_t ws_size,
                              hipStream_t stream) {
    (void)in_sizes; (void)n_in; (void)out_size; (void)ws_size;
    const float* x  = (const float*)d_in[0];
    const float* ut = (const float*)d_in[1];
    const float* up = (const float*)d_in[2];
    const float* mn = (const float*)d_in[3];
    const float* ls = (const float*)d_in[4];
    float* ws  = (float*)d_ws;
    float* out = (float*)d_out;
    float* bp  = ws + 256;
    int* bs    = (int*)(ws + 256 + (size_t)NBLK * 64);
    int* cnt   = bs + NBLK;

    hmm_setup<<<1, 64, 0, stream>>>(x, ut, up, mn, ls, ws);
    hipMemsetAsync((void*)cnt, 0, sizeof(int), stream);
    hmm_main<<<NBLK, TPB, 0, stream>>>(x, ws, bp, bs, cnt, out);
}

// Round 11
// 140.339 us; speedup vs baseline: 1.1562x; 1.1562x over previous
//
#include <hip/hip_runtime.h>
#include <math.h>

#define T_LEN 2097152
#define K 8
#define D 4
#define CHUNK 8
#define TPB 256
#define NBLK (T_LEN / (CHUNK * TPB))  // 1024 blocks
#define MSTRIDE 65                    // LDS matrix stride (floats)

// ws layout (floats): [0..63] Tr; [64..71] a; [72..103] b; [104..135] c; [136..143] alpha0
// [256..) bp (NBLK*64 floats), then bs (NBLK ints)

__device__ __forceinline__ void renorm_mat(float P[K][K], int& shift) {
    float mx = 0.f;
#pragma unroll
    for (int i = 0; i < K; ++i)
#pragma unroll
        for (int j = 0; j < K; ++j) mx = fmaxf(mx, P[i][j]);
    int ex = (__float_as_int(mx) >> 23) & 255;
    float scale = __int_as_float((254 - ex) << 23); // 2^(127-ex)
    shift += ex - 127;
#pragma unroll
    for (int i = 0; i < K; ++i)
#pragma unroll
        for (int j = 0; j < K; ++j) P[i][j] *= scale;
}

__device__ __forceinline__ void mat_combine(const float L[K][K], const float R[K][K], float C[K][K]) {
#pragma unroll
    for (int i = 0; i < K; ++i) {
        float q[K];
#pragma unroll
        for (int j = 0; j < K; ++j) q[j] = L[i][0] * R[0][j];
#pragma unroll
        for (int k = 1; k < K; ++k)
#pragma unroll
            for (int j = 0; j < K; ++j) q[j] = fmaf(L[i][k], R[k][j], q[j]);
#pragma unroll
        for (int j = 0; j < K; ++j) C[i][j] = q[j];
    }
}

__device__ __forceinline__ void combine_stream(const float* __restrict__ Lp,
                                               const float* __restrict__ Rp,
                                               float C[K][K]) {
#pragma unroll
    for (int k = 0; k < K; ++k) {
        float Lc[K], Rr[K];
#pragma unroll
        for (int i = 0; i < K; ++i) Lc[i] = Lp[i * 8 + k];
#pragma unroll
        for (int j = 0; j < K; ++j) Rr[j] = Rp[k * 8 + j];
        if (k == 0) {
#pragma unroll
            for (int i = 0; i < K; ++i)
#pragma unroll
                for (int j = 0; j < K; ++j) C[i][j] = Lc[i] * Rr[j];
        } else {
#pragma unroll
            for (int i = 0; i < K; ++i)
#pragma unroll
                for (int j = 0; j < K; ++j) C[i][j] = fmaf(Lc[i], Rr[j], C[i][j]);
        }
    }
}

// Rows-parallel reduction of 128 time-ordered matrices in LDS -> slot 0.
// 8 lanes per combine (one output row each); R-operand reads are identical
// across the 8 lanes of a group -> LDS broadcast (conflict-free).
__device__ __forceinline__ void tree_levels(float* lm, int* lsh) {
    const int g = threadIdx.x >> 3; // group 0..31 (aligned 8-lane subgroups)
    const int i = threadIdx.x & 7;  // output row
#pragma unroll 1
    for (int lvl = 1; lvl <= 7; ++lvl) {
        const int c = 64 >> (lvl - 1); // combines this level: 64..1
        const int S = 1 << (lvl - 1);
#pragma unroll 1
        for (int m = g; m < c; m += 32) {
            const int li = 2 * m * S, ri = li + S;
            const float* Lp = lm + li * MSTRIDE;
            const float* Rp = lm + ri * MSTRIDE;
            float Lr[8];
#pragma unroll
            for (int k = 0; k < 8; ++k) Lr[k] = Lp[i * 8 + k];
            float q[8];
#pragma unroll
            for (int j = 0; j < 8; ++j) q[j] = Lr[0] * Rp[j];
#pragma unroll
            for (int k = 1; k < 8; ++k)
#pragma unroll
                for (int j = 0; j < 8; ++j) q[j] = fmaf(Lr[k], Rp[k * 8 + j], q[j]);
            float mx = fmaxf(fmaxf(fmaxf(q[0], q[1]), fmaxf(q[2], q[3])),
                             fmaxf(fmaxf(q[4], q[5]), fmaxf(q[6], q[7])));
            mx = fmaxf(mx, __shfl_xor(mx, 1)); // butterfly within the 8-lane group
            mx = fmaxf(mx, __shfl_xor(mx, 2));
            mx = fmaxf(mx, __shfl_xor(mx, 4));
            int ex = (__float_as_int(mx) >> 23) & 255;
            float scale = __int_as_float((254 - ex) << 23);
            int ns = lsh[li] + lsh[ri] + (ex - 127); // reads precede lane-0 write (wave order)
            float* Op = lm + li * MSTRIDE + i * 8;
#pragma unroll
            for (int j = 0; j < 8; ++j) Op[j] = q[j] * scale;
            if (i == 0) lsh[li] = ns;
        }
        __syncthreads();
    }
}

// Level 1 (256 reg-resident mats -> 128 LDS slots, masked) + rows-parallel levels
__device__ __forceinline__ void hybrid_tree(float P[K][K], int& shift, float* lm, int* lsh) {
    const int t = threadIdx.x;
    if ((t & 1) == 0) {
#pragma unroll
        for (int i = 0; i < K; ++i)
#pragma unroll
            for (int j = 0; j < K; ++j) lm[(t >> 1) * MSTRIDE + i * 8 + j] = P[i][j];
        lsh[t >> 1] = shift;
    }
    __syncthreads();
    if (t & 1) {
        float L[K][K];
#pragma unroll
        for (int i = 0; i < K; ++i)
#pragma unroll
            for (int k = 0; k < K; ++k) L[i][k] = lm[(t >> 1) * MSTRIDE + i * 8 + k];
        float C[K][K];
        mat_combine(L, P, C); // L earlier in time
        int ns = shift + lsh[t >> 1];
        renorm_mat(C, ns);
#pragma unroll
        for (int i = 0; i < K; ++i)
#pragma unroll
            for (int j = 0; j < K; ++j) lm[(t >> 1) * MSTRIDE + i * 8 + j] = C[i][j];
        lsh[t >> 1] = ns;
    }
    __syncthreads();
    tree_levels(lm, lsh);
}

// 64-thread parallel setup (keeps main's consts uniform -> SGPR)
__global__ void hmm_setup(const float* __restrict__ x,
                          const float* __restrict__ ut,
                          const float* __restrict__ up,
                          const float* __restrict__ mn,
                          const float* __restrict__ lsd,
                          float* __restrict__ ws) {
    const int lane = threadIdx.x;
    const float L2PI = 1.83787706640934548356f;
    const float LOG2E = 1.44269504088896340736f;

    float v = ut[lane];
    float m = v;
    m = fmaxf(m, __shfl_xor(m, 1));
    m = fmaxf(m, __shfl_xor(m, 2));
    m = fmaxf(m, __shfl_xor(m, 4));
    float e = expf(v - m);
    float s = e;
    s += __shfl_xor(s, 1); s += __shfl_xor(s, 2); s += __shfl_xor(s, 4);
    ws[lane] = e / s;

    float pv = up[lane & 7];
    float pm = pv;
    pm = fmaxf(pm, __shfl_xor(pm, 1));
    pm = fmaxf(pm, __shfl_xor(pm, 2));
    pm = fmaxf(pm, __shfl_xor(pm, 4));
    float pe = expf(pv - pm);
    float ps = pe;
    ps += __shfl_xor(ps, 1); ps += __shfl_xor(ps, 2); ps += __shfl_xor(ps, 4);
    float pival = pe / ps;

    int k = (lane & 31) >> 2, d = lane & 3;
    float lv = lsd[k * D + d];
    float mu = mn[k * D + d];
    float iv = expf(-2.f * lv);
    float bn = mu * iv;
    float cn = -0.5f * iv;
    float aterm = -0.5f * L2PI - lv - 0.5f * mu * mu * iv;
    float ak = aterm;
    ak += __shfl_xor(ak, 1); ak += __shfl_xor(ak, 2);
    if (lane < 32) {
        ws[72 + lane]  = bn * LOG2E;
        ws[104 + lane] = cn * LOG2E;
        if (d == 0) ws[64 + k] = ak * LOG2E;
    }

    float xd = x[d];
    float part = (cn * xd + bn) * xd + aterm;
    part += __shfl_xor(part, 1); part += __shfl_xor(part, 2);
    float pik = __shfl(pival, k);
    if (lane < 32 && d == 0) ws[136 + k] = pik * expf(part);
}

__global__ __launch_bounds__(TPB) void hmm_main(const float* __restrict__ x,
                                                const float* __restrict__ cst,
                                                float* __restrict__ bp,
                                                int* __restrict__ bs) {
    __shared__ float lm[128 * MSTRIDE];
    __shared__ int lsh[128];
    const int tid = blockIdx.x * TPB + threadIdx.x;

    float Tr[K][K];
#pragma unroll
    for (int i = 0; i < K; ++i)
#pragma unroll
        for (int j = 0; j < K; ++j) Tr[i][j] = cst[i * K + j];
    float ca[K], cb[K][D], cc[K][D];
#pragma unroll
    for (int k = 0; k < K; ++k) {
        ca[k] = cst[64 + k];
#pragma unroll
        for (int d = 0; d < D; ++d) {
            cb[k][d] = cst[72 + k * D + d];
            cc[k][d] = cst[104 + k * D + d];
        }
    }

    const float4* xv = reinterpret_cast<const float4*>(x) + (size_t)tid * CHUNK;

    float P[K][K];
    int shift = 0;
    if (tid == 0) {
#pragma unroll
        for (int i = 0; i < K; ++i)
#pragma unroll
            for (int j = 0; j < K; ++j) P[i][j] = (i == j) ? cst[136 + i] : 0.0f;
    } else {
        float4 x0 = xv[0];
        float e[K];
#pragma unroll
        for (int j = 0; j < K; ++j) {
            float em = ca[j];
            em = fmaf(fmaf(cc[j][0], x0.x, cb[j][0]), x0.x, em);
            em = fmaf(fmaf(cc[j][1], x0.y, cb[j][1]), x0.y, em);
            em = fmaf(fmaf(cc[j][2], x0.z, cb[j][2]), x0.z, em);
            em = fmaf(fmaf(cc[j][3], x0.w, cb[j][3]), x0.w, em);
            e[j] = exp2f(em);
        }
#pragma unroll
        for (int i = 0; i < K; ++i)
#pragma unroll
            for (int j = 0; j < K; ++j) P[i][j] = Tr[i][j] * e[j];
    }

    // scan: P <- (P*Tr) .col e_t ; pow2 renorm every 2nd step folded into next e
    float fcarry = 0.0f;
    int icarry = 0;
    float4 xnext = xv[1];
#pragma unroll 1
    for (int t = 1; t < CHUNK; ++t) {
        float4 xt = xnext;
        int tn = (t + 1 < CHUNK) ? (t + 1) : t;
        xnext = xv[tn];
        float e[K];
#pragma unroll
        for (int j = 0; j < K; ++j) {
            float em = ca[j];
            em = fmaf(fmaf(cc[j][0], xt.x, cb[j][0]), xt.x, em);
            em = fmaf(fmaf(cc[j][1], xt.y, cb[j][1]), xt.y, em);
            em = fmaf(fmaf(cc[j][2], xt.z, cb[j][2]), xt.z, em);
            em = fmaf(fmaf(cc[j][3], xt.w, cb[j][3]), xt.w, em);
            e[j] = exp2f(em + fcarry);
        }
        shift -= icarry;
#pragma unroll
        for (int i = 0; i < K; ++i) {
            float q[K];
#pragma unroll
            for (int j = 0; j < K; ++j) q[j] = P[i][0] * Tr[0][j];
#pragma unroll
            for (int k = 1; k < K; ++k)
#pragma unroll
                for (int j = 0; j < K; ++j) q[j] = fmaf(P[i][k], Tr[k][j], q[j]);
#pragma unroll
            for (int j = 0; j < K; ++j) P[i][j] = q[j] * e[j];
        }
        if ((t & 1) == 0) {
            float mx = 0.f;
#pragma unroll
            for (int i = 0; i < K; ++i)
#pragma unroll
                for (int j = 0; j < K; ++j) mx = fmaxf(mx, P[i][j]);
            int ex = (__float_as_int(mx) >> 23) & 255;
            icarry = 127 - ex;
            fcarry = (float)icarry;
        } else {
            icarry = 0;
            fcarry = 0.0f;
        }
    }
    renorm_mat(P, shift);

    hybrid_tree(P, shift, lm, lsh);

    if (threadIdx.x == 0) {
        float4* o4 = reinterpret_cast<float4*>(bp + (size_t)blockIdx.x * 64);
        const float4* l4 = reinterpret_cast<const float4*>(lm);
#pragma unroll
        for (int q = 0; q < 16; ++q) o4[q] = l4[q];
        bs[blockIdx.x] = lsh[0];
    }
}

// 256-thread final: 4 serial combines per thread, then the hybrid tree
__global__ void hmm_final(const float* __restrict__ bp,
                          const int* __restrict__ bs,
                          float* __restrict__ out) {
    __shared__ float lm[128 * MSTRIDE];
    __shared__ int lsh[128];
    const int t = threadIdx.x;
    const int base = t * 4;

    float P[K][K];
    {
        const float4* p4 = reinterpret_cast<const float4*>(bp + (size_t)base * 64);
        float4* dst = reinterpret_cast<float4*>(&P[0][0]);
#pragma unroll
        for (int q = 0; q < 16; ++q) dst[q] = p4[q];
    }
    int shift = bs[base];
#pragma unroll 1
    for (int r = 1; r < 4; ++r) {
        const float* Rp = bp + (size_t)(base + r) * 64;
        float C[K][K];
        combine_stream(&P[0][0], Rp, C);
        shift += bs[base + r];
        renorm_mat(C, shift);
#pragma unroll
        for (int i = 0; i < K; ++i)
#pragma unroll
            for (int j = 0; j < K; ++j) P[i][j] = C[i][j];
    }

    hybrid_tree(P, shift, lm, lsh);

    if (t == 0) {
        double s = 0.0;
#pragma unroll
        for (int i = 0; i < K; ++i)
#pragma unroll
            for (int j = 0; j < K; ++j) s += (double)lm[i * 8 + j];
        out[0] = (float)(log(s) + (double)lsh[0] * 0.69314718055994530942);
    }
}

extern "C" void kernel_launch(void* const* d_in, const int* in_sizes, int n_in,
                              void* d_out, int out_size, void* d_ws, size_t ws_size,
                              hipStream_t stream) {
    (void)in_sizes; (void)n_in; (void)out_size; (void)ws_size;
    const float* x  = (const float*)d_in[0];
    const float* ut = (const float*)d_in[1];
    const float* up = (const float*)d_in[2];
    const float* mn = (const float*)d_in[3];
    const float* ls = (const float*)d_in[4];
    float* ws  = (float*)d_ws;
    float* out = (float*)d_out;
    float* bp  = ws + 256;
    int* bs    = (int*)(ws + 256 + (size_t)NBLK * 64);

    hmm_setup<<<1, 64, 0, stream>>>(x, ut, up, mn, ls, ws);
    hmm_main<<<NBLK, TPB, 0, stream>>>(x, ws, bp, bs);
    hmm_final<<<1, TPB, 0, stream>>>(bp, bs, out);
}

// Round 12
// 138.929 us; speedup vs baseline: 1.1679x; 1.0102x over previous
//
#include <hip/hip_runtime.h>
#include <math.h>

#define T_LEN 2097152
#define K 8
#define D 4
#define CHUNK 8
#define TPB 256
#define NBLK (T_LEN / (CHUNK * TPB))  // 1024 blocks
#define MSTRIDE 65                    // LDS matrix stride (floats)

// ws layout (floats): [0..63] Tr; [64..71] a; [72..103] b; [104..135] c; [136..143] alpha0
// [256..) bp (NBLK*64 floats), then bs (NBLK floats)

__device__ __forceinline__ void renorm_matf(float P[K][K], float& shift) {
    float mx = 0.f;
#pragma unroll
    for (int i = 0; i < K; ++i)
#pragma unroll
        for (int j = 0; j < K; ++j) mx = fmaxf(mx, P[i][j]);
    int ex = (__float_as_int(mx) >> 23) & 255;
    float scale = __int_as_float((254 - ex) << 23); // 2^(127-ex)
    shift += (float)(ex - 127);
#pragma unroll
    for (int i = 0; i < K; ++i)
#pragma unroll
        for (int j = 0; j < K; ++j) P[i][j] *= scale;
}

__device__ __forceinline__ void mat_combine(const float L[K][K], const float R[K][K], float C[K][K]) {
#pragma unroll
    for (int i = 0; i < K; ++i) {
        float q[K];
#pragma unroll
        for (int j = 0; j < K; ++j) q[j] = L[i][0] * R[0][j];
#pragma unroll
        for (int k = 1; k < K; ++k)
#pragma unroll
            for (int j = 0; j < K; ++j) q[j] = fmaf(L[i][k], R[k][j], q[j]);
#pragma unroll
        for (int j = 0; j < K; ++j) C[i][j] = q[j];
    }
}

__device__ __forceinline__ void combine_stream(const float* __restrict__ Lp,
                                               const float* __restrict__ Rp,
                                               float C[K][K]) {
#pragma unroll
    for (int k = 0; k < K; ++k) {
        float Lc[K], Rr[K];
#pragma unroll
        for (int i = 0; i < K; ++i) Lc[i] = Lp[i * 8 + k];
#pragma unroll
        for (int j = 0; j < K; ++j) Rr[j] = Rp[k * 8 + j];
        if (k == 0) {
#pragma unroll
            for (int i = 0; i < K; ++i)
#pragma unroll
                for (int j = 0; j < K; ++j) C[i][j] = Lc[i] * Rr[j];
        } else {
#pragma unroll
            for (int i = 0; i < K; ++i)
#pragma unroll
                for (int j = 0; j < K; ++j) C[i][j] = fmaf(Lc[i], Rr[j], C[i][j]);
        }
    }
}

// Rows-parallel reduction of 128 time-ordered matrices in LDS -> slot 0.
// 8 lanes per combine (one output row each); R reads broadcast across the group.
__device__ __forceinline__ void tree_levels(float* lm, float* lsh) {
    const int g = threadIdx.x >> 3; // group 0..31
    const int i = threadIdx.x & 7;  // output row
#pragma unroll 1
    for (int lvl = 1; lvl <= 7; ++lvl) {
        const int c = 64 >> (lvl - 1);
        const int S = 1 << (lvl - 1);
#pragma unroll 1
        for (int m = g; m < c; m += 32) {
            const int li = 2 * m * S, ri = li + S;
            const float* Lp = lm + li * MSTRIDE;
            const float* Rp = lm + ri * MSTRIDE;
            float Lr[8];
#pragma unroll
            for (int k = 0; k < 8; ++k) Lr[k] = Lp[i * 8 + k];
            float q[8];
#pragma unroll
            for (int j = 0; j < 8; ++j) q[j] = Lr[0] * Rp[j];
#pragma unroll
            for (int k = 1; k < 8; ++k)
#pragma unroll
                for (int j = 0; j < 8; ++j) q[j] = fmaf(Lr[k], Rp[k * 8 + j], q[j]);
            float mx = fmaxf(fmaxf(fmaxf(q[0], q[1]), fmaxf(q[2], q[3])),
                             fmaxf(fmaxf(q[4], q[5]), fmaxf(q[6], q[7])));
            mx = fmaxf(mx, __shfl_xor(mx, 1));
            mx = fmaxf(mx, __shfl_xor(mx, 2));
            mx = fmaxf(mx, __shfl_xor(mx, 4));
            int ex = (__float_as_int(mx) >> 23) & 255;
            float scale = __int_as_float((254 - ex) << 23);
            float ns = lsh[li] + lsh[ri] + (float)(ex - 127); // reads precede lane-0 write
            float* Op = lm + li * MSTRIDE + i * 8;
#pragma unroll
            for (int j = 0; j < 8; ++j) Op[j] = q[j] * scale;
            if (i == 0) lsh[li] = ns;
        }
        __syncthreads();
    }
}

// Level 1 (256 reg-resident mats -> 128 LDS slots, masked) + rows-parallel levels
__device__ __forceinline__ void hybrid_tree(float P[K][K], float& shift, float* lm, float* lsh) {
    const int t = threadIdx.x;
    if ((t & 1) == 0) {
#pragma unroll
        for (int i = 0; i < K; ++i)
#pragma unroll
            for (int j = 0; j < K; ++j) lm[(t >> 1) * MSTRIDE + i * 8 + j] = P[i][j];
        lsh[t >> 1] = shift;
    }
    __syncthreads();
    if (t & 1) {
        float L[K][K];
#pragma unroll
        for (int i = 0; i < K; ++i)
#pragma unroll
            for (int k = 0; k < K; ++k) L[i][k] = lm[(t >> 1) * MSTRIDE + i * 8 + k];
        float C[K][K];
        mat_combine(L, P, C); // L earlier in time
        float ns = shift + lsh[t >> 1];
        renorm_matf(C, ns);
#pragma unroll
        for (int i = 0; i < K; ++i)
#pragma unroll
            for (int j = 0; j < K; ++j) lm[(t >> 1) * MSTRIDE + i * 8 + j] = C[i][j];
        lsh[t >> 1] = ns;
    }
    __syncthreads();
    tree_levels(lm, lsh);
}

// emission e[8] (log2-domain, max-normalized); returns the subtracted max
__device__ __forceinline__ float emit_e(const float ca[K], const float cb[K][D],
                                        const float cc[K][D], float4 x, float e[K]) {
    float em[K];
#pragma unroll
    for (int j = 0; j < K; ++j) {
        float t = ca[j];
        t = fmaf(fmaf(cc[j][0], x.x, cb[j][0]), x.x, t);
        t = fmaf(fmaf(cc[j][1], x.y, cb[j][1]), x.y, t);
        t = fmaf(fmaf(cc[j][2], x.z, cb[j][2]), x.z, t);
        t = fmaf(fmaf(cc[j][3], x.w, cb[j][3]), x.w, t);
        em[j] = t;
    }
    float me = fmaxf(fmaxf(fmaxf(em[0], em[1]), fmaxf(em[2], em[3])),
                     fmaxf(fmaxf(em[4], em[5]), fmaxf(em[6], em[7])));
#pragma unroll
    for (int j = 0; j < K; ++j) e[j] = exp2f(em[j] - me);
    return me;
}

// 64-thread parallel setup (keeps main's consts uniform -> SGPR)
__global__ void hmm_setup(const float* __restrict__ x,
                          const float* __restrict__ ut,
                          const float* __restrict__ up,
                          const float* __restrict__ mn,
                          const float* __restrict__ lsd,
                          float* __restrict__ ws) {
    const int lane = threadIdx.x;
    const float L2PI = 1.83787706640934548356f;
    const float LOG2E = 1.44269504088896340736f;

    float v = ut[lane];
    float m = v;
    m = fmaxf(m, __shfl_xor(m, 1));
    m = fmaxf(m, __shfl_xor(m, 2));
    m = fmaxf(m, __shfl_xor(m, 4));
    float e = expf(v - m);
    float s = e;
    s += __shfl_xor(s, 1); s += __shfl_xor(s, 2); s += __shfl_xor(s, 4);
    ws[lane] = e / s;

    float pv = up[lane & 7];
    float pm = pv;
    pm = fmaxf(pm, __shfl_xor(pm, 1));
    pm = fmaxf(pm, __shfl_xor(pm, 2));
    pm = fmaxf(pm, __shfl_xor(pm, 4));
    float pe = expf(pv - pm);
    float ps = pe;
    ps += __shfl_xor(ps, 1); ps += __shfl_xor(ps, 2); ps += __shfl_xor(ps, 4);
    float pival = pe / ps;

    int k = (lane & 31) >> 2, d = lane & 3;
    float lv = lsd[k * D + d];
    float mu = mn[k * D + d];
    float iv = expf(-2.f * lv);
    float bn = mu * iv;
    float cn = -0.5f * iv;
    float aterm = -0.5f * L2PI - lv - 0.5f * mu * mu * iv;
    float ak = aterm;
    ak += __shfl_xor(ak, 1); ak += __shfl_xor(ak, 2);
    if (lane < 32) {
        ws[72 + lane]  = bn * LOG2E;
        ws[104 + lane] = cn * LOG2E;
        if (d == 0) ws[64 + k] = ak * LOG2E;
    }

    float xd = x[d];
    float part = (cn * xd + bn) * xd + aterm;
    part += __shfl_xor(part, 1); part += __shfl_xor(part, 2);
    float pik = __shfl(pival, k);
    if (lane < 32 && d == 0) ws[136 + k] = pik * expf(part);
}

__global__ __launch_bounds__(TPB) void hmm_main(const float* __restrict__ x,
                                                const float* __restrict__ cst,
                                                float* __restrict__ bp,
                                                float* __restrict__ bs) {
    __shared__ float lm[128 * MSTRIDE];
    __shared__ float lsh[128];
    const int tid = blockIdx.x * TPB + threadIdx.x;

    float Tr[K][K];
#pragma unroll
    for (int i = 0; i < K; ++i)
#pragma unroll
        for (int j = 0; j < K; ++j) Tr[i][j] = cst[i * K + j];
    float ca[K], cb[K][D], cc[K][D];
#pragma unroll
    for (int k = 0; k < K; ++k) {
        ca[k] = cst[64 + k];
#pragma unroll
        for (int d = 0; d < D; ++d) {
            cb[k][d] = cst[72 + k * D + d];
            cc[k][d] = cst[104 + k * D + d];
        }
    }

    const float4* xv = reinterpret_cast<const float4*>(x) + (size_t)tid * CHUNK;

    // Chunk transfer = Tr * S0 * S1 * S2 * S3, S = D_a*Tr*D_b (2 steps each).
    // T starts as S0; 3 folds T <- ((T.col eA) * Tr) .col eB; final G = Tr*T.
    // Thread 0: leading diag(alpha0) replaces (Tr*D_0) -> no final Tr.
    float T[K][K];
    float shift;
    {
        float4 xa = xv[0];
        float4 xb = xv[1];
        float eB[K];
        float meB = emit_e(ca, cb, cc, xb, eB);
        if (tid == 0) {
#pragma unroll
            for (int i = 0; i < K; ++i) {
                float a0 = cst[136 + i];
#pragma unroll
                for (int j = 0; j < K; ++j) T[i][j] = a0 * Tr[i][j] * eB[j];
            }
            shift = meB;
        } else {
            float eA[K];
            float meA = emit_e(ca, cb, cc, xa, eA);
#pragma unroll
            for (int i = 0; i < K; ++i) {
#pragma unroll
                for (int j = 0; j < K; ++j) T[i][j] = eA[i] * Tr[i][j] * eB[j];
            }
            shift = meA + meB;
        }
    }

#pragma unroll
    for (int p = 1; p < 4; ++p) {
        float4 xa = xv[2 * p];
        float4 xb = xv[2 * p + 1];
        float eA[K], eB[K];
        float meA = emit_e(ca, cb, cc, xa, eA);
        float meB = emit_e(ca, cb, cc, xb, eB);
        shift += meA + meB;
        // T <- ((T .col eA) * Tr) .col eB, row-wise in place (Tr from SGPRs)
#pragma unroll
        for (int i = 0; i < K; ++i) {
            float r[K];
#pragma unroll
            for (int k = 0; k < K; ++k) r[k] = T[i][k] * eA[k];
            float u[K];
#pragma unroll
            for (int j = 0; j < K; ++j) u[j] = r[0] * Tr[0][j];
#pragma unroll
            for (int k = 1; k < K; ++k)
#pragma unroll
                for (int j = 0; j < K; ++j) u[j] = fmaf(r[k], Tr[k][j], u[j]);
#pragma unroll
            for (int j = 0; j < K; ++j) T[i][j] = u[j] * eB[j];
        }
    }

    if (tid != 0) {
        // T <- Tr * T, column-wise in place (Tr from SGPRs, +8 regs)
#pragma unroll
        for (int j = 0; j < K; ++j) {
            float c[K];
#pragma unroll
            for (int k = 0; k < K; ++k) c[k] = T[k][j];
#pragma unroll
            for (int i = 0; i < K; ++i) {
                float a = Tr[i][0] * c[0];
#pragma unroll
                for (int k = 1; k < K; ++k) a = fmaf(Tr[i][k], c[k], a);
                T[i][j] = a;
            }
        }
    }
    renorm_matf(T, shift);

    hybrid_tree(T, shift, lm, lsh);

    if (threadIdx.x == 0) {
        float4* o4 = reinterpret_cast<float4*>(bp + (size_t)blockIdx.x * 64);
        const float4* l4 = reinterpret_cast<const float4*>(lm);
#pragma unroll
        for (int q = 0; q < 16; ++q) o4[q] = l4[q];
        bs[blockIdx.x] = lsh[0];
    }
}

// 256-thread final: 4 serial combines per thread, then the hybrid tree
__global__ void hmm_final(const float* __restrict__ bp,
                          const float* __restrict__ bs,
                          float* __restrict__ out) {
    __shared__ float lm[128 * MSTRIDE];
    __shared__ float lsh[128];
    const int t = threadIdx.x;
    const int base = t * 4;

    float P[K][K];
    {
        const float4* p4 = reinterpret_cast<const float4*>(bp + (size_t)base * 64);
        float4* dst = reinterpret_cast<float4*>(&P[0][0]);
#pragma unroll
        for (int q = 0; q < 16; ++q) dst[q] = p4[q];
    }
    float shift = bs[base];
#pragma unroll 1
    for (int r = 1; r < 4; ++r) {
        const float* Rp = bp + (size_t)(base + r) * 64;
        float C[K][K];
        combine_stream(&P[0][0], Rp, C);
        shift += bs[base + r];
        renorm_matf(C, shift);
#pragma unroll
        for (int i = 0; i < K; ++i)
#pragma unroll
            for (int j = 0; j < K; ++j) P[i][j] = C[i][j];
    }

    hybrid_tree(P, shift, lm, lsh);

    if (t == 0) {
        double s = 0.0;
#pragma unroll
        for (int i = 0; i < K; ++i)
#pragma unroll
            for (int j = 0; j < K; ++j) s += (double)lm[i * 8 + j];
        out[0] = (float)(log(s) + (double)lsh[0] * 0.69314718055994530942);
    }
}

extern "C" void kernel_launch(void* const* d_in, const int* in_sizes, int n_in,
                              void* d_out, int out_size, void* d_ws, size_t ws_size,
                              hipStream_t stream) {
    (void)in_sizes; (void)n_in; (void)out_size; (void)ws_size;
    const float* x  = (const float*)d_in[0];
    const float* ut = (const float*)d_in[1];
    const float* up = (const float*)d_in[2];
    const float* mn = (const float*)d_in[3];
    const float* ls = (const float*)d_in[4];
    float* ws  = (float*)d_ws;
    float* out = (float*)d_out;
    float* bp  = ws + 256;
    float* bs  = ws + 256 + (size_t)NBLK * 64;

    hmm_setup<<<1, 64, 0, stream>>>(x, ut, up, mn, ls, ws);
    hmm_main<<<NBLK, TPB, 0, stream>>>(x, ws, bp, bs);
    hmm_final<<<1, TPB, 0, stream>>>(bp, bs, out);
}

// Round 13
// 134.835 us; speedup vs baseline: 1.2034x; 1.0304x over previous
//
#include <hip/hip_runtime.h>
#include <math.h>

#define T_LEN 2097152
#define K 8
#define D 4
#define CHUNK 8
#define TPB 256
#define NBLK (T_LEN / (CHUNK * TPB))  // 1024 blocks
#define MSTRIDE 65                    // LDS matrix stride (floats)

typedef float f2 __attribute__((ext_vector_type(2)));

__device__ __forceinline__ f2 fma2(f2 a, f2 b, f2 c) { return __builtin_elementwise_fma(a, b, c); }
__device__ __forceinline__ f2 max2(f2 a, f2 b) { return __builtin_elementwise_max(a, b); }
__device__ __forceinline__ f2 splat(float s) { f2 r; r.x = s; r.y = s; return r; }

// ws layout (floats): [0..63] Tr; [64..71] a; [72..103] b; [104..135] c; [136..143] alpha0
// [256..) bp (NBLK*64 floats), then bs (NBLK floats)

__device__ __forceinline__ void renorm_matf(float P[K][K], float& shift) {
    float mx = 0.f;
#pragma unroll
    for (int i = 0; i < K; ++i)
#pragma unroll
        for (int j = 0; j < K; ++j) mx = fmaxf(mx, P[i][j]);
    int ex = (__float_as_int(mx) >> 23) & 255;
    float scale = __int_as_float((254 - ex) << 23); // 2^(127-ex)
    shift += (float)(ex - 127);
#pragma unroll
    for (int i = 0; i < K; ++i)
#pragma unroll
        for (int j = 0; j < K; ++j) P[i][j] *= scale;
}

__device__ __forceinline__ void mat_combine(const float L[K][K], const float R[K][K], float C[K][K]) {
#pragma unroll
    for (int i = 0; i < K; ++i) {
        float q[K];
#pragma unroll
        for (int j = 0; j < K; ++j) q[j] = L[i][0] * R[0][j];
#pragma unroll
        for (int k = 1; k < K; ++k)
#pragma unroll
            for (int j = 0; j < K; ++j) q[j] = fmaf(L[i][k], R[k][j], q[j]);
#pragma unroll
        for (int j = 0; j < K; ++j) C[i][j] = q[j];
    }
}

__device__ __forceinline__ void combine_stream(const float* __restrict__ Lp,
                                               const float* __restrict__ Rp,
                                               float C[K][K]) {
#pragma unroll
    for (int k = 0; k < K; ++k) {
        float Lc[K], Rr[K];
#pragma unroll
        for (int i = 0; i < K; ++i) Lc[i] = Lp[i * 8 + k];
#pragma unroll
        for (int j = 0; j < K; ++j) Rr[j] = Rp[k * 8 + j];
        if (k == 0) {
#pragma unroll
            for (int i = 0; i < K; ++i)
#pragma unroll
                for (int j = 0; j < K; ++j) C[i][j] = Lc[i] * Rr[j];
        } else {
#pragma unroll
            for (int i = 0; i < K; ++i)
#pragma unroll
                for (int j = 0; j < K; ++j) C[i][j] = fmaf(Lc[i], Rr[j], C[i][j]);
        }
    }
}

// Rows-parallel reduction of 128 time-ordered matrices in LDS -> slot 0.
__device__ __forceinline__ void tree_levels(float* lm, float* lsh) {
    const int g = threadIdx.x >> 3; // group 0..31
    const int i = threadIdx.x & 7;  // output row
#pragma unroll 1
    for (int lvl = 1; lvl <= 7; ++lvl) {
        const int c = 64 >> (lvl - 1);
        const int S = 1 << (lvl - 1);
#pragma unroll 1
        for (int m = g; m < c; m += 32) {
            const int li = 2 * m * S, ri = li + S;
            const float* Lp = lm + li * MSTRIDE;
            const float* Rp = lm + ri * MSTRIDE;
            float Lr[8];
#pragma unroll
            for (int k = 0; k < 8; ++k) Lr[k] = Lp[i * 8 + k];
            float q[8];
#pragma unroll
            for (int j = 0; j < 8; ++j) q[j] = Lr[0] * Rp[j];
#pragma unroll
            for (int k = 1; k < 8; ++k)
#pragma unroll
                for (int j = 0; j < 8; ++j) q[j] = fmaf(Lr[k], Rp[k * 8 + j], q[j]);
            float mx = fmaxf(fmaxf(fmaxf(q[0], q[1]), fmaxf(q[2], q[3])),
                             fmaxf(fmaxf(q[4], q[5]), fmaxf(q[6], q[7])));
            mx = fmaxf(mx, __shfl_xor(mx, 1));
            mx = fmaxf(mx, __shfl_xor(mx, 2));
            mx = fmaxf(mx, __shfl_xor(mx, 4));
            int ex = (__float_as_int(mx) >> 23) & 255;
            float scale = __int_as_float((254 - ex) << 23);
            float ns = lsh[li] + lsh[ri] + (float)(ex - 127);
            float* Op = lm + li * MSTRIDE + i * 8;
#pragma unroll
            for (int j = 0; j < 8; ++j) Op[j] = q[j] * scale;
            if (i == 0) lsh[li] = ns;
        }
        __syncthreads();
    }
}

__device__ __forceinline__ void hybrid_tree(float P[K][K], float& shift, float* lm, float* lsh) {
    const int t = threadIdx.x;
    if ((t & 1) == 0) {
#pragma unroll
        for (int i = 0; i < K; ++i)
#pragma unroll
            for (int j = 0; j < K; ++j) lm[(t >> 1) * MSTRIDE + i * 8 + j] = P[i][j];
        lsh[t >> 1] = shift;
    }
    __syncthreads();
    if (t & 1) {
        float L[K][K];
#pragma unroll
        for (int i = 0; i < K; ++i)
#pragma unroll
            for (int k = 0; k < K; ++k) L[i][k] = lm[(t >> 1) * MSTRIDE + i * 8 + k];
        float C[K][K];
        mat_combine(L, P, C); // L earlier in time
        float ns = shift + lsh[t >> 1];
        renorm_matf(C, ns);
#pragma unroll
        for (int i = 0; i < K; ++i)
#pragma unroll
            for (int j = 0; j < K; ++j) lm[(t >> 1) * MSTRIDE + i * 8 + j] = C[i][j];
        lsh[t >> 1] = ns;
    }
    __syncthreads();
    tree_levels(lm, lsh);
}

// packed emission: e2[4] = exp2(em - max), returns max (state pairs in f2)
__device__ __forceinline__ float emit_e2(const f2 ca2[4], const f2 cb2[4][4],
                                         const f2 cc2[4][4], float4 x, f2 e2[4]) {
    f2 x0 = splat(x.x), x1 = splat(x.y), x2 = splat(x.z), x3 = splat(x.w);
    f2 em2[4];
#pragma unroll
    for (int jj = 0; jj < 4; ++jj) {
        f2 t = ca2[jj];
        t = fma2(fma2(cc2[0][jj], x0, cb2[0][jj]), x0, t);
        t = fma2(fma2(cc2[1][jj], x1, cb2[1][jj]), x1, t);
        t = fma2(fma2(cc2[2][jj], x2, cb2[2][jj]), x2, t);
        t = fma2(fma2(cc2[3][jj], x3, cb2[3][jj]), x3, t);
        em2[jj] = t;
    }
    f2 m2 = max2(max2(em2[0], em2[1]), max2(em2[2], em2[3]));
    float me = fmaxf(m2.x, m2.y);
#pragma unroll
    for (int jj = 0; jj < 4; ++jj) {
        e2[jj].x = exp2f(em2[jj].x - me);
        e2[jj].y = exp2f(em2[jj].y - me);
    }
    return me;
}

// 64-thread parallel setup (keeps main's consts uniform -> SGPR)
__global__ void hmm_setup(const float* __restrict__ x,
                          const float* __restrict__ ut,
                          const float* __restrict__ up,
                          const float* __restrict__ mn,
                          const float* __restrict__ lsd,
                          float* __restrict__ ws) {
    const int lane = threadIdx.x;
    const float L2PI = 1.83787706640934548356f;
    const float LOG2E = 1.44269504088896340736f;

    float v = ut[lane];
    float m = v;
    m = fmaxf(m, __shfl_xor(m, 1));
    m = fmaxf(m, __shfl_xor(m, 2));
    m = fmaxf(m, __shfl_xor(m, 4));
    float e = expf(v - m);
    float s = e;
    s += __shfl_xor(s, 1); s += __shfl_xor(s, 2); s += __shfl_xor(s, 4);
    ws[lane] = e / s;

    float pv = up[lane & 7];
    float pm = pv;
    pm = fmaxf(pm, __shfl_xor(pm, 1));
    pm = fmaxf(pm, __shfl_xor(pm, 2));
    pm = fmaxf(pm, __shfl_xor(pm, 4));
    float pe = expf(pv - pm);
    float ps = pe;
    ps += __shfl_xor(ps, 1); ps += __shfl_xor(ps, 2); ps += __shfl_xor(ps, 4);
    float pival = pe / ps;

    int k = (lane & 31) >> 2, d = lane & 3;
    float lv = lsd[k * D + d];
    float mu = mn[k * D + d];
    float iv = expf(-2.f * lv);
    float bn = mu * iv;
    float cn = -0.5f * iv;
    float aterm = -0.5f * L2PI - lv - 0.5f * mu * mu * iv;
    float ak = aterm;
    ak += __shfl_xor(ak, 1); ak += __shfl_xor(ak, 2);
    if (lane < 32) {
        ws[72 + lane]  = bn * LOG2E;
        ws[104 + lane] = cn * LOG2E;
        if (d == 0) ws[64 + k] = ak * LOG2E;
    }

    float xd = x[d];
    float part = (cn * xd + bn) * xd + aterm;
    part += __shfl_xor(part, 1); part += __shfl_xor(part, 2);
    float pik = __shfl(pival, k);
    if (lane < 32 && d == 0) ws[136 + k] = pik * expf(part);
}

__global__ __launch_bounds__(TPB) void hmm_main(const float* __restrict__ x,
                                                const float* __restrict__ cst,
                                                float* __restrict__ bp,
                                                float* __restrict__ bs) {
    __shared__ float lm[128 * MSTRIDE];
    __shared__ float lsh[128];
    const int tid = blockIdx.x * TPB + threadIdx.x;

    float Tr[K][K]; // scalar view (uniform -> SGPR)
#pragma unroll
    for (int i = 0; i < K; ++i)
#pragma unroll
        for (int j = 0; j < K; ++j) Tr[i][j] = cst[i * K + j];
    f2 Tr2[K][4];   // packed column-pair view
#pragma unroll
    for (int i = 0; i < K; ++i)
#pragma unroll
        for (int jj = 0; jj < 4; ++jj) { Tr2[i][jj].x = Tr[i][2 * jj]; Tr2[i][jj].y = Tr[i][2 * jj + 1]; }

    f2 ca2[4], cb2[4][4], cc2[4][4]; // [d][state-pair]
#pragma unroll
    for (int jj = 0; jj < 4; ++jj) {
        ca2[jj].x = cst[64 + 2 * jj]; ca2[jj].y = cst[64 + 2 * jj + 1];
#pragma unroll
        for (int d = 0; d < 4; ++d) {
            cb2[d][jj].x = cst[72 + (2 * jj) * 4 + d];  cb2[d][jj].y = cst[72 + (2 * jj + 1) * 4 + d];
            cc2[d][jj].x = cst[104 + (2 * jj) * 4 + d]; cc2[d][jj].y = cst[104 + (2 * jj + 1) * 4 + d];
        }
    }

    // full-chunk register prefetch: one latency exposure per chunk
    const float4* xv = reinterpret_cast<const float4*>(x) + (size_t)tid * CHUNK;
    float4 xr[CHUNK];
#pragma unroll
    for (int t = 0; t < CHUNK; ++t) xr[t] = xv[t];

    // Chunk transfer = Tr*S0*S1*S2*S3, S=(D_a·Tr·D_b); T packed as f2[8][4]
    f2 T2[K][4];
    float shift;
    {
        f2 eB[4];
        float meB = emit_e2(ca2, cb2, cc2, xr[1], eB);
        if (tid == 0) {
#pragma unroll
            for (int i = 0; i < K; ++i) {
                f2 a0 = splat(cst[136 + i]);
#pragma unroll
                for (int jj = 0; jj < 4; ++jj) T2[i][jj] = a0 * Tr2[i][jj] * eB[jj];
            }
            shift = meB;
        } else {
            f2 eA[4];
            float meA = emit_e2(ca2, cb2, cc2, xr[0], eA);
#pragma unroll
            for (int i = 0; i < K; ++i) {
                f2 ei = splat((i & 1) ? eA[i >> 1].y : eA[i >> 1].x);
#pragma unroll
                for (int jj = 0; jj < 4; ++jj) T2[i][jj] = ei * Tr2[i][jj] * eB[jj];
            }
            shift = meA + meB;
        }
    }

#pragma unroll
    for (int p = 1; p < 4; ++p) {
        f2 eA[4], eB[4];
        float meA = emit_e2(ca2, cb2, cc2, xr[2 * p], eA);
        float meB = emit_e2(ca2, cb2, cc2, xr[2 * p + 1], eB);
        shift += meA + meB;
        // T <- ((T .col eA) * Tr) .col eB, row-wise in place
#pragma unroll
        for (int i = 0; i < K; ++i) {
            f2 r2[4];
#pragma unroll
            for (int kk = 0; kk < 4; ++kk) r2[kk] = T2[i][kk] * eA[kk];
            f2 u[4];
#pragma unroll
            for (int jj = 0; jj < 4; ++jj) u[jj] = splat(r2[0].x) * Tr2[0][jj];
#pragma unroll
            for (int k = 1; k < 8; ++k) {
                f2 rk = splat((k & 1) ? r2[k >> 1].y : r2[k >> 1].x);
#pragma unroll
                for (int jj = 0; jj < 4; ++jj) u[jj] = fma2(rk, Tr2[k][jj], u[jj]);
            }
#pragma unroll
            for (int jj = 0; jj < 4; ++jj) T2[i][jj] = u[jj] * eB[jj];
        }
    }

    if (tid != 0) {
        // T <- Tr * T, column-pair in place
#pragma unroll
        for (int jj = 0; jj < 4; ++jj) {
            f2 c[K];
#pragma unroll
            for (int k = 0; k < K; ++k) c[k] = T2[k][jj];
#pragma unroll
            for (int i = 0; i < K; ++i) {
                f2 a = splat(Tr[i][0]) * c[0];
#pragma unroll
                for (int k = 1; k < K; ++k) a = fma2(splat(Tr[i][k]), c[k], a);
                T2[i][jj] = a;
            }
        }
    }

    float (*T)[K] = reinterpret_cast<float(*)[K]>(T2); // layout-compatible
    renorm_matf(T, shift);

    hybrid_tree(T, shift, lm, lsh);

    if (threadIdx.x == 0) {
        float4* o4 = reinterpret_cast<float4*>(bp + (size_t)blockIdx.x * 64);
        const float4* l4 = reinterpret_cast<const float4*>(lm);
#pragma unroll
        for (int q = 0; q < 16; ++q) o4[q] = l4[q];
        bs[blockIdx.x] = lsh[0];
    }
}

// 256-thread final: 4 serial combines per thread, then the hybrid tree
__global__ void hmm_final(const float* __restrict__ bp,
                          const float* __restrict__ bs,
                          float* __restrict__ out) {
    __shared__ float lm[128 * MSTRIDE];
    __shared__ float lsh[128];
    const int t = threadIdx.x;
    const int base = t * 4;

    float P[K][K];
    {
        const float4* p4 = reinterpret_cast<const float4*>(bp + (size_t)base * 64);
        float4* dst = reinterpret_cast<float4*>(&P[0][0]);
#pragma unroll
        for (int q = 0; q < 16; ++q) dst[q] = p4[q];
    }
    float shift = bs[base];
#pragma unroll 1
    for (int r = 1; r < 4; ++r) {
        const float* Rp = bp + (size_t)(base + r) * 64;
        float C[K][K];
        combine_stream(&P[0][0], Rp, C);
        shift += bs[base + r];
        renorm_matf(C, shift);
#pragma unroll
        for (int i = 0; i < K; ++i)
#pragma unroll
            for (int j = 0; j < K; ++j) P[i][j] = C[i][j];
    }

    hybrid_tree(P, shift, lm, lsh);

    if (t == 0) {
        double s = 0.0;
#pragma unroll
        for (int i = 0; i < K; ++i)
#pragma unroll
            for (int j = 0; j < K; ++j) s += (double)lm[i * 8 + j];
        out[0] = (float)(log(s) + (double)lsh[0] * 0.69314718055994530942);
    }
}

extern "C" void kernel_launch(void* const* d_in, const int* in_sizes, int n_in,
                              void* d_out, int out_size, void* d_ws, size_t ws_size,
                              hipStream_t stream) {
    (void)in_sizes; (void)n_in; (void)out_size; (void)ws_size;
    const float* x  = (const float*)d_in[0];
    const float* ut = (const float*)d_in[1];
    const float* up = (const float*)d_in[2];
    const float* mn = (const float*)d_in[3];
    const float* ls = (const float*)d_in[4];
    float* ws  = (float*)d_ws;
    float* out = (float*)d_out;
    float* bp  = ws + 256;
    float* bs  = ws + 256 + (size_t)NBLK * 64;

    hmm_setup<<<1, 64, 0, stream>>>(x, ut, up, mn, ls, ws);
    hmm_main<<<NBLK, TPB, 0, stream>>>(x, ws, bp, bs);
    hmm_final<<<1, TPB, 0, stream>>>(bp, bs, out);
}